// Round 4
// baseline (568.362 us; speedup 1.0000x reference)
//
#include <hip/hip_runtime.h>
#include <stdint.h>

// ---------------------------------------------------------------------------
// OwnMultiHeadTransformer: B=4, S=2048, D=1024, H=16, HD=64, FF=4096
// fp32 I/O, bf16 MFMA internal.
//   0) cvt_all: fp32 inputs -> bf16 in d_ws
//   1) gemm128<2>: QKV projection; Q scaled by log2e/32; V stored transposed
//   2) flash_attn: no-max exp2 softmax, S^T orientation (R3)
//   3) gemm128<1>: FFN1 + relu
//   4) gemm128<0>: FFN2 -> d_out (fp32)
// R4: (a) XCD-aware block swizzle (rows = lid&7 mod 8 per XCD, col-panels) for
//     L2 locality; (b) fragment-linear LDS layout in gemm128 — frag reads are
//     base + lane*16B (conflict-free by construction, same content as before).
// ---------------------------------------------------------------------------

typedef __attribute__((ext_vector_type(8))) short bf16x8;
typedef __attribute__((ext_vector_type(4))) float f32x4;

__device__ __forceinline__ float bf2f(unsigned short u) {
  union { float f; uint32_t i; } v; v.i = ((uint32_t)u) << 16; return v.f;
}
__device__ __forceinline__ unsigned short f2bf(float f) {
  union { float f; uint32_t i; } v; v.f = f;
  uint32_t i = v.i;
  return (unsigned short)((i + 0x7fffu + ((i >> 16) & 1u)) >> 16);  // RNE
}

#if __has_builtin(__builtin_amdgcn_exp2f)
#define EXP2(x) __builtin_amdgcn_exp2f(x)
#else
#define EXP2(x) __expf((x) * 0.6931471805599453f)
#endif

// pack two f32 -> two bf16 (round-half-up) in one u32; lo gets p0
__device__ __forceinline__ uint32_t pk_bf16(float p0, float p1) {
  union { float f; uint32_t i; } a, b; a.f = p0; b.f = p1;
  return __builtin_amdgcn_perm(b.i + 0x8000u, a.i + 0x8000u, 0x07060302u);
}

// async 16B global->LDS (wave-uniform base + lane*16 via tid-linear chunks)
__device__ __forceinline__ void gld16(const void* g, void* l) {
  __builtin_amdgcn_global_load_lds(
      (const __attribute__((address_space(1))) uint32_t*)(uintptr_t)g,
      (__attribute__((address_space(3))) uint32_t*)(uintptr_t)l, 16, 0, 0);
}

#define SCALE_Q 0.04508422002778011f  /* log2(e) / sqrt(D=1024) */

// ---- ws layout (bf16 element offsets) -------------------------------------
#define W1B          0
#define W2B    4194304
#define B1B    8388608
#define B2B    8392704
#define BQB    8393728
#define BKB    8394752
#define BVB    8395776
#define EMBB   8396800
#define WQB   16785408
#define WKB   17833984
#define WVB   18882560
#define QOFF  19931136
#define KOFF  28319744
#define VTOFF 36708352
#define HCOFF 45096960        /* peak 53485568 elems = 102 MiB */
#define HIDOFF 8396800        /* hid overlays dead emb/Wqkv regions */

// ---- 0) fp32 -> bf16 ------------------------------------------------------
__global__ void cvt_all(const float* __restrict__ emb, const float* __restrict__ Wq,
                        const float* __restrict__ bq,  const float* __restrict__ Wk,
                        const float* __restrict__ bk,  const float* __restrict__ Wv,
                        const float* __restrict__ bv,  const float* __restrict__ W1,
                        const float* __restrict__ b1,  const float* __restrict__ W2,
                        const float* __restrict__ b2,  unsigned short* __restrict__ ws) {
  const int i4 = blockIdx.x * 256 + threadIdx.x;
  if (i4 >= 4982784) return;
  const float* s; unsigned short* d; int base;
  if      (i4 < 2097152) { s = emb; d = ws + EMBB; base = 0; }
  else if (i4 < 2359296) { s = Wq;  d = ws + WQB;  base = 2097152; }
  else if (i4 < 2621440) { s = Wk;  d = ws + WKB;  base = 2359296; }
  else if (i4 < 2883584) { s = Wv;  d = ws + WVB;  base = 2621440; }
  else if (i4 < 3932160) { s = W1;  d = ws + W1B;  base = 2883584; }
  else if (i4 < 4980736) { s = W2;  d = ws + W2B;  base = 3932160; }
  else if (i4 < 4980992) { s = bq;  d = ws + BQB;  base = 4980736; }
  else if (i4 < 4981248) { s = bk;  d = ws + BKB;  base = 4980992; }
  else if (i4 < 4981504) { s = bv;  d = ws + BVB;  base = 4981248; }
  else if (i4 < 4982528) { s = b1;  d = ws + B1B;  base = 4981504; }
  else                   { s = b2;  d = ws + B2B;  base = 4982528; }
  const int j = i4 - base;
  const float4 v = ((const float4*)s)[j];
  ushort4 o;
  o.x = f2bf(v.x); o.y = f2bf(v.y); o.z = f2bf(v.z); o.w = f2bf(v.w);
  *(ushort4*)(d + (size_t)j * 4) = o;
}

// ---- GEMM: MODE 0 = bias (fp32 out), 1 = bias+relu, 2 = QKV routing -------
// Requires gridDim.y == 64 (rows) for the XCD swizzle.
template <int MODE>
__launch_bounds__(256, 2)
__global__ void gemm128(const unsigned short* __restrict__ A,
                        const unsigned short* __restrict__ W0,
                        const unsigned short* __restrict__ W1p,
                        const unsigned short* __restrict__ W2p,
                        const unsigned short* __restrict__ bias0,
                        const unsigned short* __restrict__ bias1,
                        const unsigned short* __restrict__ bias2,
                        unsigned short* __restrict__ out0,
                        unsigned short* __restrict__ out1,
                        unsigned short* __restrict__ out2,
                        float* __restrict__ foutp,
                        int N, int K) {
  __shared__ unsigned short At[128 * 32];
  __shared__ unsigned short Bt[128 * 32];
  const int tid  = threadIdx.x;
  const int wave = tid >> 6, lane = tid & 63;
  const int quad = lane >> 4, l15 = lane & 15;

  // XCD swizzle: xcd = lid&7 owns rows ≡ xcd (mod 8), iterated in col-panels
  // of 8 -> per-XCD resident working set = 8 A-tiles + 8 W-tiles (<= 4MiB L2).
  const int lid = blockIdx.x + blockIdx.y * gridDim.x;
  const int s_ = lid >> 3;
  const int rowBase = (((lid & 7) + ((s_ & 7) << 3)) << 7);
  const int colBase = ((s_ >> 3) << 7);

  const unsigned short* W = W0;
  const unsigned short* bias = bias0;
  int colW = colBase;
  if (MODE == 2) {
    const int which = colBase >> 10;
    if (which == 1) { W = W1p; bias = bias1; }
    if (which == 2) { W = W2p; bias = bias2; }
    colW = colBase & 1023;
  }

  // Fragment-linear staging: chunk u (16B) holds (r, c) with
  //   r = (u>>6)*16 + (u&15), c = (u>>4)&3; stored at LDS + u*16B.
  // Frag read for row r=base+l15, chunk=quad is then base16 + lane*16B.
  const int u0 = tid, u1 = tid + 256;
  const int r0 = ((u0 >> 6) << 4) | (u0 & 15), c0 = (u0 >> 4) & 3;
  const int r1 = ((u1 >> 6) << 4) | (u1 & 15), c1 = (u1 >> 4) & 3;
  const unsigned short* gA0 = A + (size_t)(rowBase + r0) * K + c0 * 8;
  const unsigned short* gA1 = A + (size_t)(rowBase + r1) * K + c1 * 8;
  const unsigned short* gB0 = W + (size_t)(colW + r0) * K + c0 * 8;
  const unsigned short* gB1 = W + (size_t)(colW + r1) * K + c1 * 8;
  unsigned short* lA0 = At + u0 * 8;
  unsigned short* lA1 = At + u1 * 8;
  unsigned short* lB0 = Bt + u0 * 8;
  unsigned short* lB1 = Bt + u1 * 8;

  const int wrow = (wave & 1) * 64, wcol = (wave >> 1) * 64;
  int aoff[4], boff[4];
#pragma unroll
  for (int t = 0; t < 4; ++t) {
    aoff[t] = ((wrow >> 4) + t) * 512 + lane * 8;
    boff[t] = ((wcol >> 4) + t) * 512 + lane * 8;
  }

  f32x4 acc[4][4] = {};
  for (int k0 = 0; k0 < K; k0 += 32) {
    __syncthreads();
    gld16(gA0, lA0); gld16(gA1, lA1);
    gld16(gB0, lB0); gld16(gB1, lB1);
    gA0 += 32; gA1 += 32; gB0 += 32; gB1 += 32;
    __syncthreads();
    bf16x8 af[4], bfr[4];
#pragma unroll
    for (int t = 0; t < 4; ++t) af[t]  = *(const bf16x8*)(At + aoff[t]);
#pragma unroll
    for (int t = 0; t < 4; ++t) bfr[t] = *(const bf16x8*)(Bt + boff[t]);
#pragma unroll
    for (int mt = 0; mt < 4; ++mt)
#pragma unroll
      for (int nt = 0; nt < 4; ++nt)
        acc[mt][nt] = __builtin_amdgcn_mfma_f32_16x16x32_bf16(
            af[mt], bfr[nt], acc[mt][nt], 0, 0, 0);
  }

#pragma unroll
  for (int mt = 0; mt < 4; ++mt) {
    const int row = rowBase + wrow + mt * 16 + quad * 4;
#pragma unroll
    for (int nt = 0; nt < 4; ++nt) {
      const int cIn = colW + wcol + nt * 16 + l15;
      const float bv = bf2f(bias[cIn]);
      if (MODE == 2) {
        const int which = colBase >> 10;
        const int h = cIn >> 6, e = cIn & 63;
#pragma unroll
        for (int r = 0; r < 4; ++r) {
          const int tok = row + r;
          const int b = tok >> 11, s = tok & 2047;
          const float v = acc[mt][nt][r] + bv;
          const size_t bh = (size_t)(b * 16 + h);
          if (which == 0)      out0[(bh * 2048 + s) * 64 + e] = f2bf(v * SCALE_Q);
          else if (which == 1) out1[(bh * 2048 + s) * 64 + e] = f2bf(v);
          else                 out2[(bh * 64 + e) * 2048 + s] = f2bf(v);  // V^T
        }
      } else if (MODE == 1) {
#pragma unroll
        for (int r = 0; r < 4; ++r) {
          const float v = fmaxf(acc[mt][nt][r] + bv, 0.0f);
          out0[(size_t)(row + r) * N + cIn] = f2bf(v);
        }
      } else {
#pragma unroll
        for (int r = 0; r < 4; ++r)
          foutp[(size_t)(row + r) * N + cIn] = acc[mt][nt][r] + bv;
      }
    }
  }
}

// ---- flash attention (R3): S^T orientation, no-max exp2 softmax -----------
// grid (16, 64): logical (q-block, b*16+h); XCD-swizzled like the GEMMs.
__launch_bounds__(256, 4)
__global__ void flash_attn(const unsigned short* __restrict__ Q,
                           const unsigned short* __restrict__ Kg,
                           const unsigned short* __restrict__ Vt,
                           unsigned short* __restrict__ Hc) {
  __shared__ unsigned short Kt[64 * 64];     // K tile [t][e], chunk-swizzled
  __shared__ unsigned short Vs[64 * 64];     // V^T tile [e][t], chunk-swizzled
  __shared__ unsigned short Pl[4][32 * 64];  // per-wave P [q][t], chunk-swizzled
  __shared__ float Lb[4][32];                // per-wave row sums
  const int tid  = threadIdx.x;
  const int wave = tid >> 6, lane = tid & 63;
  const int quad = lane >> 4, l15 = lane & 15;

  // XCD swizzle: 8 bh's per XCD, q-blocks iterated within -> KV hot in L2.
  const int lid = blockIdx.x + blockIdx.y * gridDim.x;
  const int s_ = lid >> 3;
  const int bh = (lid & 7) + ((s_ & 7) << 3);
  const int q0 = ((s_ >> 3) << 7) + wave * 32;

  const size_t base = (size_t)bh * (2048 * 64);
  const unsigned short* Qb = Q  + base;
  const unsigned short* Kb = Kg + base;
  const unsigned short* Vb = Vt + base;   // [64 e][2048 t]

  // Q fragments (MFMA B operand for S^T: n=q=l15, k=e=quad*8+j)
  bf16x8 qf[2][2];
#pragma unroll
  for (int qt = 0; qt < 2; ++qt) {
    const int q = q0 + qt * 16 + l15;
#pragma unroll
    for (int kk = 0; kk < 2; ++kk)
      qf[qt][kk] = *(const bf16x8*)(Qb + (size_t)q * 64 + kk * 32 + quad * 8);
  }

  // KV staging (8-elem chunk swizzle: ec = cc ^ (row&7))
  const int u0 = tid, u1 = tid + 256;
  const int kr0 = u0 >> 3, kc0 = (((u0 & 7) ^ (kr0 & 7)) * 8);
  const int kr1 = u1 >> 3, kc1 = (((u1 & 7) ^ (kr1 & 7)) * 8);
  const unsigned short* gK0 = Kb + (size_t)kr0 * 64 + kc0;
  const unsigned short* gK1 = Kb + (size_t)kr1 * 64 + kc1;
  const unsigned short* gV0 = Vb + (size_t)kr0 * 2048 + kc0;
  const unsigned short* gV1 = Vb + (size_t)kr1 * 2048 + kc1;
  unsigned short* lK0 = Kt + u0 * 8;
  unsigned short* lK1 = Kt + u1 * 8;
  unsigned short* lV0 = Vs + u0 * 8;
  unsigned short* lV1 = Vs + u1 * 8;

  float l_acc[2] = {0.0f, 0.0f};
  f32x4 o[2][4] = {};
  unsigned short* Pw = Pl[wave];

  for (int it = 0; it < 32; ++it) {
    __syncthreads();
    gld16(gK0, lK0); gld16(gK1, lK1);
    gld16(gV0, lV0); gld16(gV1, lV1);
    gK0 += 4096; gK1 += 4096; gV0 += 64; gV1 += 64;
    __syncthreads();

    // S^T = K Q^T : C row = t_local = tt*16+quad*4+r, col = q = qt*16+l15
    f32x4 st[4][2] = {};
#pragma unroll
    for (int tt = 0; tt < 4; ++tt) {
      const int t = tt * 16 + l15;
      const bf16x8 kf0 = *(const bf16x8*)(Kt + t * 64 + ((quad       ^ (t & 7)) * 8));
      const bf16x8 kf1 = *(const bf16x8*)(Kt + t * 64 + (((quad + 4) ^ (t & 7)) * 8));
#pragma unroll
      for (int qt = 0; qt < 2; ++qt) {
        st[tt][qt] = __builtin_amdgcn_mfma_f32_16x16x32_bf16(kf0, qf[qt][0], st[tt][qt], 0, 0, 0);
        st[tt][qt] = __builtin_amdgcn_mfma_f32_16x16x32_bf16(kf1, qf[qt][1], st[tt][qt], 0, 0, 0);
      }
    }

    // p = exp2(s) (no max: scores bounded), lane-local l, pack -> P[q][t] LDS
#pragma unroll
    for (int tt = 0; tt < 4; ++tt) {
      const int tc = tt * 2 + (quad >> 1);
#pragma unroll
      for (int qt = 0; qt < 2; ++qt) {
        const float p0 = EXP2(st[tt][qt][0]);
        const float p1 = EXP2(st[tt][qt][1]);
        const float p2 = EXP2(st[tt][qt][2]);
        const float p3 = EXP2(st[tt][qt][3]);
        l_acc[qt] += (p0 + p1) + (p2 + p3);
        uint2 w;
        w.x = pk_bf16(p0, p1);
        w.y = pk_bf16(p2, p3);
        const int qrow = qt * 16 + l15;
        *(uint2*)(Pw + qrow * 64 + ((tc ^ (qrow & 7)) * 8) + (quad & 1) * 4) = w;
      }
    }

    // O += P V (same-wave LDS round-trip, ordered by lgkmcnt)
    bf16x8 pf[2][2];
#pragma unroll
    for (int mt = 0; mt < 2; ++mt) {
      const int qq = mt * 16 + l15;
      pf[mt][0] = *(const bf16x8*)(Pw + qq * 64 + ((quad       ^ (qq & 7)) * 8));
      pf[mt][1] = *(const bf16x8*)(Pw + qq * 64 + (((quad + 4) ^ (qq & 7)) * 8));
    }
#pragma unroll
    for (int nt = 0; nt < 4; ++nt) {
      const int e = nt * 16 + l15;
      const bf16x8 vf0 = *(const bf16x8*)(Vs + e * 64 + ((quad       ^ (e & 7)) * 8));
      const bf16x8 vf1 = *(const bf16x8*)(Vs + e * 64 + (((quad + 4) ^ (e & 7)) * 8));
#pragma unroll
      for (int mt = 0; mt < 2; ++mt) {
        o[mt][nt] = __builtin_amdgcn_mfma_f32_16x16x32_bf16(pf[mt][0], vf0, o[mt][nt], 0, 0, 0);
        o[mt][nt] = __builtin_amdgcn_mfma_f32_16x16x32_bf16(pf[mt][1], vf1, o[mt][nt], 0, 0, 0);
      }
    }
  }

  // l: reduce across quads, publish per-q via LDS, fetch per C-row
#pragma unroll
  for (int qt = 0; qt < 2; ++qt) {
    float v = l_acc[qt];
    v += __shfl_xor(v, 16, 64);
    v += __shfl_xor(v, 32, 64);
    Lb[wave][qt * 16 + l15] = v;
  }
  const f32x4 lv0 = *(const f32x4*)&Lb[wave][quad * 4];
  const f32x4 lv1 = *(const f32x4*)&Lb[wave][16 + quad * 4];

  const int b = bh >> 4, h = bh & 15;
#pragma unroll
  for (int mt = 0; mt < 2; ++mt)
#pragma unroll
    for (int r = 0; r < 4; ++r) {
      const int qg = q0 + mt * 16 + quad * 4 + r;
      const float inv = __builtin_amdgcn_rcpf(mt == 0 ? lv0[r] : lv1[r]);
#pragma unroll
      for (int nt = 0; nt < 4; ++nt) {
        const int e = nt * 16 + l15;
        Hc[((size_t)b * 2048 + qg) * 1024 + h * 64 + e] = f2bf(o[mt][nt][r] * inv);
      }
    }
}

extern "C" void kernel_launch(void* const* d_in, const int* in_sizes, int n_in,
                              void* d_out, int out_size, void* d_ws, size_t ws_size,
                              hipStream_t stream) {
  const float* emb = (const float*)d_in[0];
  const float* Wq  = (const float*)d_in[1];
  const float* bq  = (const float*)d_in[2];
  const float* Wk  = (const float*)d_in[3];
  const float* bk  = (const float*)d_in[4];
  const float* Wv  = (const float*)d_in[5];
  const float* bv  = (const float*)d_in[6];
  const float* W1  = (const float*)d_in[7];
  const float* b1  = (const float*)d_in[8];
  const float* W2  = (const float*)d_in[9];
  const float* b2  = (const float*)d_in[10];

  unsigned short* ws = (unsigned short*)d_ws;
  float* out = (float*)d_out;

  cvt_all<<<19465, 256, 0, stream>>>(emb, Wq, bq, Wk, bk, Wv, bv, W1, b1, W2, b2, ws);
  gemm128<2><<<dim3(24, 64), 256, 0, stream>>>(
      ws + EMBB, ws + WQB, ws + WKB, ws + WVB, ws + BQB, ws + BKB, ws + BVB,
      ws + QOFF, ws + KOFF, ws + VTOFF, nullptr, 3072, 1024);
  flash_attn<<<dim3(16, 64), 256, 0, stream>>>(ws + QOFF, ws + KOFF, ws + VTOFF, ws + HCOFF);
  gemm128<1><<<dim3(32, 64), 256, 0, stream>>>(
      ws + HCOFF, ws + W1B, nullptr, nullptr, ws + B1B, nullptr, nullptr,
      ws + HIDOFF, nullptr, nullptr, nullptr, 4096, 1024);
  gemm128<0><<<dim3(8, 64), 256, 0, stream>>>(
      ws + HIDOFF, ws + W2B, nullptr, nullptr, ws + B2B, nullptr, nullptr,
      nullptr, nullptr, nullptr, out, 1024, 4096);
}

// Round 5
// 470.424 us; speedup vs baseline: 1.2082x; 1.2082x over previous
//
#include <hip/hip_runtime.h>
#include <stdint.h>

// ---------------------------------------------------------------------------
// OwnMultiHeadTransformer: B=4, S=2048, D=1024, H=16, HD=64, FF=4096
// fp32 I/O, bf16 MFMA internal.
//   0) cvt_all: fp32 inputs -> bf16 in d_ws
//   1) gemm128<2>: QKV projection; Q scaled by log2e/32; V stored transposed
//   2) flash_attn: no-max exp2 softmax, S^T orientation (R3)
//   3) gemm128<1>: FFN1 + relu
//   4) gemm128<0>: FFN2 -> d_out (fp32)
// R5: staging/LDS reverted to R3 pattern (64B row-grouped lanes: 4 consecutive
//     lanes cover one row's 64B -> 16 coalesced line-requests/instr; the R4
//     fragment-linear layout scattered lanes across 16 rows -> ~4x L2 request
//     amplification, all-idle stall). XCD/panel block swizzle KEPT (FETCH
//     283->44 MB measured in R4).
// ---------------------------------------------------------------------------

typedef __attribute__((ext_vector_type(8))) short bf16x8;
typedef __attribute__((ext_vector_type(4))) float f32x4;

__device__ __forceinline__ float bf2f(unsigned short u) {
  union { float f; uint32_t i; } v; v.i = ((uint32_t)u) << 16; return v.f;
}
__device__ __forceinline__ unsigned short f2bf(float f) {
  union { float f; uint32_t i; } v; v.f = f;
  uint32_t i = v.i;
  return (unsigned short)((i + 0x7fffu + ((i >> 16) & 1u)) >> 16);  // RNE
}

#if __has_builtin(__builtin_amdgcn_exp2f)
#define EXP2(x) __builtin_amdgcn_exp2f(x)
#else
#define EXP2(x) __expf((x) * 0.6931471805599453f)
#endif

// pack two f32 -> two bf16 (round-half-up) in one u32; lo gets p0
__device__ __forceinline__ uint32_t pk_bf16(float p0, float p1) {
  union { float f; uint32_t i; } a, b; a.f = p0; b.f = p1;
  return __builtin_amdgcn_perm(b.i + 0x8000u, a.i + 0x8000u, 0x07060302u);
}

// async 16B global->LDS (wave-uniform base + lane*16 via tid-linear chunks)
__device__ __forceinline__ void gld16(const void* g, void* l) {
  __builtin_amdgcn_global_load_lds(
      (const __attribute__((address_space(1))) uint32_t*)(uintptr_t)g,
      (__attribute__((address_space(3))) uint32_t*)(uintptr_t)l, 16, 0, 0);
}

#define SCALE_Q 0.04508422002778011f  /* log2(e) / sqrt(D=1024) */

// ---- ws layout (bf16 element offsets) -------------------------------------
#define W1B          0
#define W2B    4194304
#define B1B    8388608
#define B2B    8392704
#define BQB    8393728
#define BKB    8394752
#define BVB    8395776
#define EMBB   8396800
#define WQB   16785408
#define WKB   17833984
#define WVB   18882560
#define QOFF  19931136
#define KOFF  28319744
#define VTOFF 36708352
#define HCOFF 45096960        /* peak 53485568 elems = 102 MiB */
#define HIDOFF 8396800        /* hid overlays dead emb/Wqkv regions */

// ---- 0) fp32 -> bf16 ------------------------------------------------------
__global__ void cvt_all(const float* __restrict__ emb, const float* __restrict__ Wq,
                        const float* __restrict__ bq,  const float* __restrict__ Wk,
                        const float* __restrict__ bk,  const float* __restrict__ Wv,
                        const float* __restrict__ bv,  const float* __restrict__ W1,
                        const float* __restrict__ b1,  const float* __restrict__ W2,
                        const float* __restrict__ b2,  unsigned short* __restrict__ ws) {
  const int i4 = blockIdx.x * 256 + threadIdx.x;
  if (i4 >= 4982784) return;
  const float* s; unsigned short* d; int base;
  if      (i4 < 2097152) { s = emb; d = ws + EMBB; base = 0; }
  else if (i4 < 2359296) { s = Wq;  d = ws + WQB;  base = 2097152; }
  else if (i4 < 2621440) { s = Wk;  d = ws + WKB;  base = 2359296; }
  else if (i4 < 2883584) { s = Wv;  d = ws + WVB;  base = 2621440; }
  else if (i4 < 3932160) { s = W1;  d = ws + W1B;  base = 2883584; }
  else if (i4 < 4980736) { s = W2;  d = ws + W2B;  base = 3932160; }
  else if (i4 < 4980992) { s = bq;  d = ws + BQB;  base = 4980736; }
  else if (i4 < 4981248) { s = bk;  d = ws + BKB;  base = 4980992; }
  else if (i4 < 4981504) { s = bv;  d = ws + BVB;  base = 4981248; }
  else if (i4 < 4982528) { s = b1;  d = ws + B1B;  base = 4981504; }
  else                   { s = b2;  d = ws + B2B;  base = 4982528; }
  const int j = i4 - base;
  const float4 v = ((const float4*)s)[j];
  ushort4 o;
  o.x = f2bf(v.x); o.y = f2bf(v.y); o.z = f2bf(v.z); o.w = f2bf(v.w);
  *(ushort4*)(d + (size_t)j * 4) = o;
}

// ---- GEMM: MODE 0 = bias (fp32 out), 1 = bias+relu, 2 = QKV routing -------
// Requires total-rows == 64 tile-rows for the XCD swizzle.
template <int MODE>
__launch_bounds__(256, 2)
__global__ void gemm128(const unsigned short* __restrict__ A,
                        const unsigned short* __restrict__ W0,
                        const unsigned short* __restrict__ W1p,
                        const unsigned short* __restrict__ W2p,
                        const unsigned short* __restrict__ bias0,
                        const unsigned short* __restrict__ bias1,
                        const unsigned short* __restrict__ bias2,
                        unsigned short* __restrict__ out0,
                        unsigned short* __restrict__ out1,
                        unsigned short* __restrict__ out2,
                        float* __restrict__ foutp,
                        int N, int K) {
  __shared__ unsigned short At[128 * 32];
  __shared__ unsigned short Bt[128 * 32];
  const int tid  = threadIdx.x;
  const int wave = tid >> 6, lane = tid & 63;
  const int quad = lane >> 4, l15 = lane & 15;

  // XCD swizzle: xcd = lid&7 owns rows ≡ xcd (mod 8), iterated in col-panels
  // of 8 -> per-XCD resident set ~8 A-tiles + 8 W-tiles (fits 4MiB L2).
  const int lid = blockIdx.x + blockIdx.y * gridDim.x;
  const int s_ = lid >> 3;
  const int rowBase = (((lid & 7) + ((s_ & 7) << 3)) << 7);
  const int colBase = ((s_ >> 3) << 7);

  const unsigned short* W = W0;
  const unsigned short* bias = bias0;
  int colW = colBase;
  if (MODE == 2) {
    const int which = colBase >> 10;
    if (which == 1) { W = W1p; bias = bias1; }
    if (which == 2) { W = W2p; bias = bias2; }
    colW = colBase & 1023;
  }

  // R3 staging: 512 16B chunks/tile; phys chunk u=row*4+cc holds logical
  // k-chunk ec = cc ^ ((row>>2)&3). 4 consecutive lanes = one row's 64B.
  const int u0 = tid, u1 = tid + 256;
  const int r0 = u0 >> 2, e0 = (((u0 & 3) ^ ((r0 >> 2) & 3)) * 8);
  const int r1 = u1 >> 2, e1 = (((u1 & 3) ^ ((r1 >> 2) & 3)) * 8);
  const unsigned short* gA0 = A + (size_t)(rowBase + r0) * K + e0;
  const unsigned short* gA1 = A + (size_t)(rowBase + r1) * K + e1;
  const unsigned short* gB0 = W + (size_t)(colW + r0) * K + e0;
  const unsigned short* gB1 = W + (size_t)(colW + r1) * K + e1;
  unsigned short* lA0 = At + u0 * 8;
  unsigned short* lA1 = At + u1 * 8;
  unsigned short* lB0 = Bt + u0 * 8;
  unsigned short* lB1 = Bt + u1 * 8;

  const int wrow = (wave & 1) * 64, wcol = (wave >> 1) * 64;
  int aoff[4], boff[4];
#pragma unroll
  for (int t = 0; t < 4; ++t) {
    const int ra = wrow + t * 16 + l15;
    aoff[t] = ra * 32 + ((quad ^ ((ra >> 2) & 3)) * 8);
    const int rb = wcol + t * 16 + l15;
    boff[t] = rb * 32 + ((quad ^ ((rb >> 2) & 3)) * 8);
  }

  f32x4 acc[4][4] = {};
  for (int k0 = 0; k0 < K; k0 += 32) {
    __syncthreads();
    gld16(gA0, lA0); gld16(gA1, lA1);
    gld16(gB0, lB0); gld16(gB1, lB1);
    gA0 += 32; gA1 += 32; gB0 += 32; gB1 += 32;
    __syncthreads();
    bf16x8 af[4], bfr[4];
#pragma unroll
    for (int t = 0; t < 4; ++t) af[t]  = *(const bf16x8*)(At + aoff[t]);
#pragma unroll
    for (int t = 0; t < 4; ++t) bfr[t] = *(const bf16x8*)(Bt + boff[t]);
#pragma unroll
    for (int mt = 0; mt < 4; ++mt)
#pragma unroll
      for (int nt = 0; nt < 4; ++nt)
        acc[mt][nt] = __builtin_amdgcn_mfma_f32_16x16x32_bf16(
            af[mt], bfr[nt], acc[mt][nt], 0, 0, 0);
  }

#pragma unroll
  for (int mt = 0; mt < 4; ++mt) {
    const int row = rowBase + wrow + mt * 16 + quad * 4;
#pragma unroll
    for (int nt = 0; nt < 4; ++nt) {
      const int cIn = colW + wcol + nt * 16 + l15;
      const float bv = bf2f(bias[cIn]);
      if (MODE == 2) {
        const int which = colBase >> 10;
        const int h = cIn >> 6, e = cIn & 63;
#pragma unroll
        for (int r = 0; r < 4; ++r) {
          const int tok = row + r;
          const int b = tok >> 11, s = tok & 2047;
          const float v = acc[mt][nt][r] + bv;
          const size_t bh = (size_t)(b * 16 + h);
          if (which == 0)      out0[(bh * 2048 + s) * 64 + e] = f2bf(v * SCALE_Q);
          else if (which == 1) out1[(bh * 2048 + s) * 64 + e] = f2bf(v);
          else                 out2[(bh * 64 + e) * 2048 + s] = f2bf(v);  // V^T
        }
      } else if (MODE == 1) {
#pragma unroll
        for (int r = 0; r < 4; ++r) {
          const float v = fmaxf(acc[mt][nt][r] + bv, 0.0f);
          out0[(size_t)(row + r) * N + cIn] = f2bf(v);
        }
      } else {
#pragma unroll
        for (int r = 0; r < 4; ++r)
          foutp[(size_t)(row + r) * N + cIn] = acc[mt][nt][r] + bv;
      }
    }
  }
}

// ---- flash attention (R3): S^T orientation, no-max exp2 softmax -----------
// grid (16, 64): logical (q-block, b*16+h); XCD-swizzled.
__launch_bounds__(256, 4)
__global__ void flash_attn(const unsigned short* __restrict__ Q,
                           const unsigned short* __restrict__ Kg,
                           const unsigned short* __restrict__ Vt,
                           unsigned short* __restrict__ Hc) {
  __shared__ unsigned short Kt[64 * 64];     // K tile [t][e], chunk-swizzled
  __shared__ unsigned short Vs[64 * 64];     // V^T tile [e][t], chunk-swizzled
  __shared__ unsigned short Pl[4][32 * 64];  // per-wave P [q][t], chunk-swizzled
  __shared__ float Lb[4][32];                // per-wave row sums
  const int tid  = threadIdx.x;
  const int wave = tid >> 6, lane = tid & 63;
  const int quad = lane >> 4, l15 = lane & 15;

  // XCD swizzle: 8 bh's per XCD, q-blocks iterated within -> KV hot in L2.
  const int lid = blockIdx.x + blockIdx.y * gridDim.x;
  const int s_ = lid >> 3;
  const int bh = (lid & 7) + ((s_ & 7) << 3);
  const int q0 = ((s_ >> 3) << 7) + wave * 32;

  const size_t base = (size_t)bh * (2048 * 64);
  const unsigned short* Qb = Q  + base;
  const unsigned short* Kb = Kg + base;
  const unsigned short* Vb = Vt + base;   // [64 e][2048 t]

  // Q fragments (MFMA B operand for S^T: n=q=l15, k=e=quad*8+j)
  bf16x8 qf[2][2];
#pragma unroll
  for (int qt = 0; qt < 2; ++qt) {
    const int q = q0 + qt * 16 + l15;
#pragma unroll
    for (int kk = 0; kk < 2; ++kk)
      qf[qt][kk] = *(const bf16x8*)(Qb + (size_t)q * 64 + kk * 32 + quad * 8);
  }

  // KV staging (8-elem chunk swizzle: ec = cc ^ (row&7); 8 lanes = one 128B row)
  const int u0 = tid, u1 = tid + 256;
  const int kr0 = u0 >> 3, kc0 = (((u0 & 7) ^ (kr0 & 7)) * 8);
  const int kr1 = u1 >> 3, kc1 = (((u1 & 7) ^ (kr1 & 7)) * 8);
  const unsigned short* gK0 = Kb + (size_t)kr0 * 64 + kc0;
  const unsigned short* gK1 = Kb + (size_t)kr1 * 64 + kc1;
  const unsigned short* gV0 = Vb + (size_t)kr0 * 2048 + kc0;
  const unsigned short* gV1 = Vb + (size_t)kr1 * 2048 + kc1;
  unsigned short* lK0 = Kt + u0 * 8;
  unsigned short* lK1 = Kt + u1 * 8;
  unsigned short* lV0 = Vs + u0 * 8;
  unsigned short* lV1 = Vs + u1 * 8;

  float l_acc[2] = {0.0f, 0.0f};
  f32x4 o[2][4] = {};
  unsigned short* Pw = Pl[wave];

  for (int it = 0; it < 32; ++it) {
    __syncthreads();
    gld16(gK0, lK0); gld16(gK1, lK1);
    gld16(gV0, lV0); gld16(gV1, lV1);
    gK0 += 4096; gK1 += 4096; gV0 += 64; gV1 += 64;
    __syncthreads();

    // S^T = K Q^T : C row = t_local = tt*16+quad*4+r, col = q = qt*16+l15
    f32x4 st[4][2] = {};
#pragma unroll
    for (int tt = 0; tt < 4; ++tt) {
      const int t = tt * 16 + l15;
      const bf16x8 kf0 = *(const bf16x8*)(Kt + t * 64 + ((quad       ^ (t & 7)) * 8));
      const bf16x8 kf1 = *(const bf16x8*)(Kt + t * 64 + (((quad + 4) ^ (t & 7)) * 8));
#pragma unroll
      for (int qt = 0; qt < 2; ++qt) {
        st[tt][qt] = __builtin_amdgcn_mfma_f32_16x16x32_bf16(kf0, qf[qt][0], st[tt][qt], 0, 0, 0);
        st[tt][qt] = __builtin_amdgcn_mfma_f32_16x16x32_bf16(kf1, qf[qt][1], st[tt][qt], 0, 0, 0);
      }
    }

    // p = exp2(s) (no max: scores bounded), lane-local l, pack -> P[q][t] LDS
#pragma unroll
    for (int tt = 0; tt < 4; ++tt) {
      const int tc = tt * 2 + (quad >> 1);
#pragma unroll
      for (int qt = 0; qt < 2; ++qt) {
        const float p0 = EXP2(st[tt][qt][0]);
        const float p1 = EXP2(st[tt][qt][1]);
        const float p2 = EXP2(st[tt][qt][2]);
        const float p3 = EXP2(st[tt][qt][3]);
        l_acc[qt] += (p0 + p1) + (p2 + p3);
        uint2 w;
        w.x = pk_bf16(p0, p1);
        w.y = pk_bf16(p2, p3);
        const int qrow = qt * 16 + l15;
        *(uint2*)(Pw + qrow * 64 + ((tc ^ (qrow & 7)) * 8) + (quad & 1) * 4) = w;
      }
    }

    // O += P V (same-wave LDS round-trip, ordered by lgkmcnt)
    bf16x8 pf[2][2];
#pragma unroll
    for (int mt = 0; mt < 2; ++mt) {
      const int qq = mt * 16 + l15;
      pf[mt][0] = *(const bf16x8*)(Pw + qq * 64 + ((quad       ^ (qq & 7)) * 8));
      pf[mt][1] = *(const bf16x8*)(Pw + qq * 64 + (((quad + 4) ^ (qq & 7)) * 8));
    }
#pragma unroll
    for (int nt = 0; nt < 4; ++nt) {
      const int e = nt * 16 + l15;
      const bf16x8 vf0 = *(const bf16x8*)(Vs + e * 64 + ((quad       ^ (e & 7)) * 8));
      const bf16x8 vf1 = *(const bf16x8*)(Vs + e * 64 + (((quad + 4) ^ (e & 7)) * 8));
#pragma unroll
      for (int mt = 0; mt < 2; ++mt) {
        o[mt][nt] = __builtin_amdgcn_mfma_f32_16x16x32_bf16(pf[mt][0], vf0, o[mt][nt], 0, 0, 0);
        o[mt][nt] = __builtin_amdgcn_mfma_f32_16x16x32_bf16(pf[mt][1], vf1, o[mt][nt], 0, 0, 0);
      }
    }
  }

  // l: reduce across quads, publish per-q via LDS, fetch per C-row
#pragma unroll
  for (int qt = 0; qt < 2; ++qt) {
    float v = l_acc[qt];
    v += __shfl_xor(v, 16, 64);
    v += __shfl_xor(v, 32, 64);
    Lb[wave][qt * 16 + l15] = v;
  }
  const f32x4 lv0 = *(const f32x4*)&Lb[wave][quad * 4];
  const f32x4 lv1 = *(const f32x4*)&Lb[wave][16 + quad * 4];

  const int b = bh >> 4, h = bh & 15;
#pragma unroll
  for (int mt = 0; mt < 2; ++mt)
#pragma unroll
    for (int r = 0; r < 4; ++r) {
      const int qg = q0 + mt * 16 + quad * 4 + r;
      const float inv = __builtin_amdgcn_rcpf(mt == 0 ? lv0[r] : lv1[r]);
#pragma unroll
      for (int nt = 0; nt < 4; ++nt) {
        const int e = nt * 16 + l15;
        Hc[((size_t)b * 2048 + qg) * 1024 + h * 64 + e] = f2bf(o[mt][nt][r] * inv);
      }
    }
}

extern "C" void kernel_launch(void* const* d_in, const int* in_sizes, int n_in,
                              void* d_out, int out_size, void* d_ws, size_t ws_size,
                              hipStream_t stream) {
  const float* emb = (const float*)d_in[0];
  const float* Wq  = (const float*)d_in[1];
  const float* bq  = (const float*)d_in[2];
  const float* Wk  = (const float*)d_in[3];
  const float* bk  = (const float*)d_in[4];
  const float* Wv  = (const float*)d_in[5];
  const float* bv  = (const float*)d_in[6];
  const float* W1  = (const float*)d_in[7];
  const float* b1  = (const float*)d_in[8];
  const float* W2  = (const float*)d_in[9];
  const float* b2  = (const float*)d_in[10];

  unsigned short* ws = (unsigned short*)d_ws;
  float* out = (float*)d_out;

  cvt_all<<<19465, 256, 0, stream>>>(emb, Wq, bq, Wk, bk, Wv, bv, W1, b1, W2, b2, ws);
  gemm128<2><<<dim3(24, 64), 256, 0, stream>>>(
      ws + EMBB, ws + WQB, ws + WKB, ws + WVB, ws + BQB, ws + BKB, ws + BVB,
      ws + QOFF, ws + KOFF, ws + VTOFF, nullptr, 3072, 1024);
  flash_attn<<<dim3(16, 64), 256, 0, stream>>>(ws + QOFF, ws + KOFF, ws + VTOFF, ws + HCOFF);
  gemm128<1><<<dim3(32, 64), 256, 0, stream>>>(
      ws + HCOFF, ws + W1B, nullptr, nullptr, ws + B1B, nullptr, nullptr,
      ws + HIDOFF, nullptr, nullptr, nullptr, 4096, 1024);
  gemm128<0><<<dim3(8, 64), 256, 0, stream>>>(
      ws + HIDOFF, ws + W2B, nullptr, nullptr, ws + B2B, nullptr, nullptr,
      nullptr, nullptr, nullptr, out, 1024, 4096);
}

// Round 6
// 427.901 us; speedup vs baseline: 1.3283x; 1.0994x over previous
//
#include <hip/hip_runtime.h>
#include <stdint.h>

// ---------------------------------------------------------------------------
// OwnMultiHeadTransformer: B=4, S=2048, D=1024, H=16, HD=64, FF=4096
// fp32 I/O, bf16 MFMA internal.
//   0) cvt_all: fp32 inputs -> bf16 in d_ws
//   1) gemm128<2>: QKV projection; Q scaled by log2e/32; V stored transposed
//   2) flash_attn: no-max exp2 softmax, S^T orientation (R3)
//   3) gemm128<1>: FFN1 + relu
//   4) gemm128<0>: FFN2 -> d_out (fp32)
// R6: BK 32->64 in gemm128. Rationale (counters): flash's 128B-row/8-chunk-xor
//     LDS shows 0 conflicts, gemm's 64B-row showed 8.4M (64B row = 16 banks =
//     >=4-way aliasing; 128B row = 32 banks = 2-way = free per m136). BK=64
//     gives gemm the 128B-row geometry AND halves barrier count (drain tax)
//     with 2x MFMA per barrier. Staging: 8 consecutive lanes = one 128B row
//     (coalescing preserved — R4 lesson). LDS 32KB/block.
// ---------------------------------------------------------------------------

typedef __attribute__((ext_vector_type(8))) short bf16x8;
typedef __attribute__((ext_vector_type(4))) float f32x4;

__device__ __forceinline__ float bf2f(unsigned short u) {
  union { float f; uint32_t i; } v; v.i = ((uint32_t)u) << 16; return v.f;
}
__device__ __forceinline__ unsigned short f2bf(float f) {
  union { float f; uint32_t i; } v; v.f = f;
  uint32_t i = v.i;
  return (unsigned short)((i + 0x7fffu + ((i >> 16) & 1u)) >> 16);  // RNE
}

#if __has_builtin(__builtin_amdgcn_exp2f)
#define EXP2(x) __builtin_amdgcn_exp2f(x)
#else
#define EXP2(x) __expf((x) * 0.6931471805599453f)
#endif

// pack two f32 -> two bf16 (round-half-up) in one u32; lo gets p0
__device__ __forceinline__ uint32_t pk_bf16(float p0, float p1) {
  union { float f; uint32_t i; } a, b; a.f = p0; b.f = p1;
  return __builtin_amdgcn_perm(b.i + 0x8000u, a.i + 0x8000u, 0x07060302u);
}

// async 16B global->LDS (wave-uniform base + lane*16 via tid-linear chunks)
__device__ __forceinline__ void gld16(const void* g, void* l) {
  __builtin_amdgcn_global_load_lds(
      (const __attribute__((address_space(1))) uint32_t*)(uintptr_t)g,
      (__attribute__((address_space(3))) uint32_t*)(uintptr_t)l, 16, 0, 0);
}

#define SCALE_Q 0.04508422002778011f  /* log2(e) / sqrt(D=1024) */

// ---- ws layout (bf16 element offsets) -------------------------------------
#define W1B          0
#define W2B    4194304
#define B1B    8388608
#define B2B    8392704
#define BQB    8393728
#define BKB    8394752
#define BVB    8395776
#define EMBB   8396800
#define WQB   16785408
#define WKB   17833984
#define WVB   18882560
#define QOFF  19931136
#define KOFF  28319744
#define VTOFF 36708352
#define HCOFF 45096960        /* peak 53485568 elems = 102 MiB */
#define HIDOFF 8396800        /* hid overlays dead emb/Wqkv regions */

// ---- 0) fp32 -> bf16 ------------------------------------------------------
__global__ void cvt_all(const float* __restrict__ emb, const float* __restrict__ Wq,
                        const float* __restrict__ bq,  const float* __restrict__ Wk,
                        const float* __restrict__ bk,  const float* __restrict__ Wv,
                        const float* __restrict__ bv,  const float* __restrict__ W1,
                        const float* __restrict__ b1,  const float* __restrict__ W2,
                        const float* __restrict__ b2,  unsigned short* __restrict__ ws) {
  const int i4 = blockIdx.x * 256 + threadIdx.x;
  if (i4 >= 4982784) return;
  const float* s; unsigned short* d; int base;
  if      (i4 < 2097152) { s = emb; d = ws + EMBB; base = 0; }
  else if (i4 < 2359296) { s = Wq;  d = ws + WQB;  base = 2097152; }
  else if (i4 < 2621440) { s = Wk;  d = ws + WKB;  base = 2359296; }
  else if (i4 < 2883584) { s = Wv;  d = ws + WVB;  base = 2621440; }
  else if (i4 < 3932160) { s = W1;  d = ws + W1B;  base = 2883584; }
  else if (i4 < 4980736) { s = W2;  d = ws + W2B;  base = 3932160; }
  else if (i4 < 4980992) { s = bq;  d = ws + BQB;  base = 4980736; }
  else if (i4 < 4981248) { s = bk;  d = ws + BKB;  base = 4980992; }
  else if (i4 < 4981504) { s = bv;  d = ws + BVB;  base = 4981248; }
  else if (i4 < 4982528) { s = b1;  d = ws + B1B;  base = 4981504; }
  else                   { s = b2;  d = ws + B2B;  base = 4982528; }
  const int j = i4 - base;
  const float4 v = ((const float4*)s)[j];
  ushort4 o;
  o.x = f2bf(v.x); o.y = f2bf(v.y); o.z = f2bf(v.z); o.w = f2bf(v.w);
  *(ushort4*)(d + (size_t)j * 4) = o;
}

// ---- GEMM: MODE 0 = bias (fp32 out), 1 = bias+relu, 2 = QKV routing -------
// 128x128 tile, BK=64. Requires K % 64 == 0 and 64 total row-tiles.
template <int MODE>
__launch_bounds__(256, 2)
__global__ void gemm128(const unsigned short* __restrict__ A,
                        const unsigned short* __restrict__ W0,
                        const unsigned short* __restrict__ W1p,
                        const unsigned short* __restrict__ W2p,
                        const unsigned short* __restrict__ bias0,
                        const unsigned short* __restrict__ bias1,
                        const unsigned short* __restrict__ bias2,
                        unsigned short* __restrict__ out0,
                        unsigned short* __restrict__ out1,
                        unsigned short* __restrict__ out2,
                        float* __restrict__ foutp,
                        int N, int K) {
  __shared__ unsigned short At[128 * 64];
  __shared__ unsigned short Bt[128 * 64];
  const int tid  = threadIdx.x;
  const int wave = tid >> 6, lane = tid & 63;
  const int quad = lane >> 4, l15 = lane & 15;

  // XCD swizzle: xcd = lid&7 owns rows ≡ xcd (mod 8), col-panels of 8.
  const int lid = blockIdx.x + blockIdx.y * gridDim.x;
  const int s_ = lid >> 3;
  const int rowBase = (((lid & 7) + ((s_ & 7) << 3)) << 7);
  const int colBase = ((s_ >> 3) << 7);

  const unsigned short* W = W0;
  const unsigned short* bias = bias0;
  int colW = colBase;
  if (MODE == 2) {
    const int which = colBase >> 10;
    if (which == 1) { W = W1p; bias = bias1; }
    if (which == 2) { W = W2p; bias = bias2; }
    colW = colBase & 1023;
  }

  // Staging: 1024 16B chunks/tile; phys chunk u = row*8 + cc holds logical
  // k-chunk ec = cc ^ (row&7). 8 consecutive lanes = one row's full 128B.
  const unsigned short* gA[4]; const unsigned short* gB[4];
  unsigned short *lA[4], *lB[4];
#pragma unroll
  for (int i = 0; i < 4; ++i) {
    const int u = tid + 256 * i;
    const int r = u >> 3, e = (((u & 7) ^ (r & 7)) * 8);
    gA[i] = A + (size_t)(rowBase + r) * K + e;
    gB[i] = W + (size_t)(colW + r) * K + e;
    lA[i] = At + u * 8;
    lB[i] = Bt + u * 8;
  }

  // Fragment offsets: row ra, logical k-chunk q8 = quad + 4*kk ->
  // addr = ra*64 + ((q8 ^ (ra&7))*8). 128B rows -> worst 2-way (free).
  const int wrow = (wave & 1) * 64, wcol = (wave >> 1) * 64;
  int aoff[2][4], boff[2][4];
#pragma unroll
  for (int kk = 0; kk < 2; ++kk)
#pragma unroll
    for (int t = 0; t < 4; ++t) {
      const int ra = wrow + t * 16 + l15;
      aoff[kk][t] = ra * 64 + (((quad + 4 * kk) ^ (ra & 7)) * 8);
      const int rb = wcol + t * 16 + l15;
      boff[kk][t] = rb * 64 + (((quad + 4 * kk) ^ (rb & 7)) * 8);
    }

  f32x4 acc[4][4] = {};
  for (int k0 = 0; k0 < K; k0 += 64) {
    __syncthreads();
#pragma unroll
    for (int i = 0; i < 4; ++i) { gld16(gA[i], lA[i]); gld16(gB[i], lB[i]); }
#pragma unroll
    for (int i = 0; i < 4; ++i) { gA[i] += 64; gB[i] += 64; }
    __syncthreads();
#pragma unroll
    for (int kk = 0; kk < 2; ++kk) {
      bf16x8 af[4], bfr[4];
#pragma unroll
      for (int t = 0; t < 4; ++t) af[t]  = *(const bf16x8*)(At + aoff[kk][t]);
#pragma unroll
      for (int t = 0; t < 4; ++t) bfr[t] = *(const bf16x8*)(Bt + boff[kk][t]);
#pragma unroll
      for (int mt = 0; mt < 4; ++mt)
#pragma unroll
        for (int nt = 0; nt < 4; ++nt)
          acc[mt][nt] = __builtin_amdgcn_mfma_f32_16x16x32_bf16(
              af[mt], bfr[nt], acc[mt][nt], 0, 0, 0);
    }
  }

#pragma unroll
  for (int mt = 0; mt < 4; ++mt) {
    const int row = rowBase + wrow + mt * 16 + quad * 4;
#pragma unroll
    for (int nt = 0; nt < 4; ++nt) {
      const int cIn = colW + wcol + nt * 16 + l15;
      const float bv = bf2f(bias[cIn]);
      if (MODE == 2) {
        const int which = colBase >> 10;
        const int h = cIn >> 6, e = cIn & 63;
#pragma unroll
        for (int r = 0; r < 4; ++r) {
          const int tok = row + r;
          const int b = tok >> 11, s = tok & 2047;
          const float v = acc[mt][nt][r] + bv;
          const size_t bh = (size_t)(b * 16 + h);
          if (which == 0)      out0[(bh * 2048 + s) * 64 + e] = f2bf(v * SCALE_Q);
          else if (which == 1) out1[(bh * 2048 + s) * 64 + e] = f2bf(v);
          else                 out2[(bh * 64 + e) * 2048 + s] = f2bf(v);  // V^T
        }
      } else if (MODE == 1) {
#pragma unroll
        for (int r = 0; r < 4; ++r) {
          const float v = fmaxf(acc[mt][nt][r] + bv, 0.0f);
          out0[(size_t)(row + r) * N + cIn] = f2bf(v);
        }
      } else {
#pragma unroll
        for (int r = 0; r < 4; ++r)
          foutp[(size_t)(row + r) * N + cIn] = acc[mt][nt][r] + bv;
      }
    }
  }
}

// ---- flash attention (R3): S^T orientation, no-max exp2 softmax -----------
// grid (16, 64): logical (q-block, b*16+h); XCD-swizzled.
__launch_bounds__(256, 4)
__global__ void flash_attn(const unsigned short* __restrict__ Q,
                           const unsigned short* __restrict__ Kg,
                           const unsigned short* __restrict__ Vt,
                           unsigned short* __restrict__ Hc) {
  __shared__ unsigned short Kt[64 * 64];     // K tile [t][e], chunk-swizzled
  __shared__ unsigned short Vs[64 * 64];     // V^T tile [e][t], chunk-swizzled
  __shared__ unsigned short Pl[4][32 * 64];  // per-wave P [q][t], chunk-swizzled
  __shared__ float Lb[4][32];                // per-wave row sums
  const int tid  = threadIdx.x;
  const int wave = tid >> 6, lane = tid & 63;
  const int quad = lane >> 4, l15 = lane & 15;

  // XCD swizzle: 8 bh's per XCD, q-blocks iterated within -> KV hot in L2.
  const int lid = blockIdx.x + blockIdx.y * gridDim.x;
  const int s_ = lid >> 3;
  const int bh = (lid & 7) + ((s_ & 7) << 3);
  const int q0 = ((s_ >> 3) << 7) + wave * 32;

  const size_t base = (size_t)bh * (2048 * 64);
  const unsigned short* Qb = Q  + base;
  const unsigned short* Kb = Kg + base;
  const unsigned short* Vb = Vt + base;   // [64 e][2048 t]

  // Q fragments (MFMA B operand for S^T: n=q=l15, k=e=quad*8+j)
  bf16x8 qf[2][2];
#pragma unroll
  for (int qt = 0; qt < 2; ++qt) {
    const int q = q0 + qt * 16 + l15;
#pragma unroll
    for (int kk = 0; kk < 2; ++kk)
      qf[qt][kk] = *(const bf16x8*)(Qb + (size_t)q * 64 + kk * 32 + quad * 8);
  }

  // KV staging (8-elem chunk swizzle: ec = cc ^ (row&7); 8 lanes = one 128B row)
  const int u0 = tid, u1 = tid + 256;
  const int kr0 = u0 >> 3, kc0 = (((u0 & 7) ^ (kr0 & 7)) * 8);
  const int kr1 = u1 >> 3, kc1 = (((u1 & 7) ^ (kr1 & 7)) * 8);
  const unsigned short* gK0 = Kb + (size_t)kr0 * 64 + kc0;
  const unsigned short* gK1 = Kb + (size_t)kr1 * 64 + kc1;
  const unsigned short* gV0 = Vb + (size_t)kr0 * 2048 + kc0;
  const unsigned short* gV1 = Vb + (size_t)kr1 * 2048 + kc1;
  unsigned short* lK0 = Kt + u0 * 8;
  unsigned short* lK1 = Kt + u1 * 8;
  unsigned short* lV0 = Vs + u0 * 8;
  unsigned short* lV1 = Vs + u1 * 8;

  float l_acc[2] = {0.0f, 0.0f};
  f32x4 o[2][4] = {};
  unsigned short* Pw = Pl[wave];

  for (int it = 0; it < 32; ++it) {
    __syncthreads();
    gld16(gK0, lK0); gld16(gK1, lK1);
    gld16(gV0, lV0); gld16(gV1, lV1);
    gK0 += 4096; gK1 += 4096; gV0 += 64; gV1 += 64;
    __syncthreads();

    // S^T = K Q^T : C row = t_local = tt*16+quad*4+r, col = q = qt*16+l15
    f32x4 st[4][2] = {};
#pragma unroll
    for (int tt = 0; tt < 4; ++tt) {
      const int t = tt * 16 + l15;
      const bf16x8 kf0 = *(const bf16x8*)(Kt + t * 64 + ((quad       ^ (t & 7)) * 8));
      const bf16x8 kf1 = *(const bf16x8*)(Kt + t * 64 + (((quad + 4) ^ (t & 7)) * 8));
#pragma unroll
      for (int qt = 0; qt < 2; ++qt) {
        st[tt][qt] = __builtin_amdgcn_mfma_f32_16x16x32_bf16(kf0, qf[qt][0], st[tt][qt], 0, 0, 0);
        st[tt][qt] = __builtin_amdgcn_mfma_f32_16x16x32_bf16(kf1, qf[qt][1], st[tt][qt], 0, 0, 0);
      }
    }

    // p = exp2(s) (no max: scores bounded), lane-local l, pack -> P[q][t] LDS
#pragma unroll
    for (int tt = 0; tt < 4; ++tt) {
      const int tc = tt * 2 + (quad >> 1);
#pragma unroll
      for (int qt = 0; qt < 2; ++qt) {
        const float p0 = EXP2(st[tt][qt][0]);
        const float p1 = EXP2(st[tt][qt][1]);
        const float p2 = EXP2(st[tt][qt][2]);
        const float p3 = EXP2(st[tt][qt][3]);
        l_acc[qt] += (p0 + p1) + (p2 + p3);
        uint2 w;
        w.x = pk_bf16(p0, p1);
        w.y = pk_bf16(p2, p3);
        const int qrow = qt * 16 + l15;
        *(uint2*)(Pw + qrow * 64 + ((tc ^ (qrow & 7)) * 8) + (quad & 1) * 4) = w;
      }
    }

    // O += P V (same-wave LDS round-trip, ordered by lgkmcnt)
    bf16x8 pf[2][2];
#pragma unroll
    for (int mt = 0; mt < 2; ++mt) {
      const int qq = mt * 16 + l15;
      pf[mt][0] = *(const bf16x8*)(Pw + qq * 64 + ((quad       ^ (qq & 7)) * 8));
      pf[mt][1] = *(const bf16x8*)(Pw + qq * 64 + (((quad + 4) ^ (qq & 7)) * 8));
    }
#pragma unroll
    for (int nt = 0; nt < 4; ++nt) {
      const int e = nt * 16 + l15;
      const bf16x8 vf0 = *(const bf16x8*)(Vs + e * 64 + ((quad       ^ (e & 7)) * 8));
      const bf16x8 vf1 = *(const bf16x8*)(Vs + e * 64 + (((quad + 4) ^ (e & 7)) * 8));
#pragma unroll
      for (int mt = 0; mt < 2; ++mt) {
        o[mt][nt] = __builtin_amdgcn_mfma_f32_16x16x32_bf16(pf[mt][0], vf0, o[mt][nt], 0, 0, 0);
        o[mt][nt] = __builtin_amdgcn_mfma_f32_16x16x32_bf16(pf[mt][1], vf1, o[mt][nt], 0, 0, 0);
      }
    }
  }

  // l: reduce across quads, publish per-q via LDS, fetch per C-row
#pragma unroll
  for (int qt = 0; qt < 2; ++qt) {
    float v = l_acc[qt];
    v += __shfl_xor(v, 16, 64);
    v += __shfl_xor(v, 32, 64);
    Lb[wave][qt * 16 + l15] = v;
  }
  const f32x4 lv0 = *(const f32x4*)&Lb[wave][quad * 4];
  const f32x4 lv1 = *(const f32x4*)&Lb[wave][16 + quad * 4];

  const int b = bh >> 4, h = bh & 15;
#pragma unroll
  for (int mt = 0; mt < 2; ++mt)
#pragma unroll
    for (int r = 0; r < 4; ++r) {
      const int qg = q0 + mt * 16 + quad * 4 + r;
      const float inv = __builtin_amdgcn_rcpf(mt == 0 ? lv0[r] : lv1[r]);
#pragma unroll
      for (int nt = 0; nt < 4; ++nt) {
        const int e = nt * 16 + l15;
        Hc[((size_t)b * 2048 + qg) * 1024 + h * 64 + e] = f2bf(o[mt][nt][r] * inv);
      }
    }
}

extern "C" void kernel_launch(void* const* d_in, const int* in_sizes, int n_in,
                              void* d_out, int out_size, void* d_ws, size_t ws_size,
                              hipStream_t stream) {
  const float* emb = (const float*)d_in[0];
  const float* Wq  = (const float*)d_in[1];
  const float* bq  = (const float*)d_in[2];
  const float* Wk  = (const float*)d_in[3];
  const float* bk  = (const float*)d_in[4];
  const float* Wv  = (const float*)d_in[5];
  const float* bv  = (const float*)d_in[6];
  const float* W1  = (const float*)d_in[7];
  const float* b1  = (const float*)d_in[8];
  const float* W2  = (const float*)d_in[9];
  const float* b2  = (const float*)d_in[10];

  unsigned short* ws = (unsigned short*)d_ws;
  float* out = (float*)d_out;

  cvt_all<<<19465, 256, 0, stream>>>(emb, Wq, bq, Wk, bk, Wv, bv, W1, b1, W2, b2, ws);
  gemm128<2><<<dim3(24, 64), 256, 0, stream>>>(
      ws + EMBB, ws + WQB, ws + WKB, ws + WVB, ws + BQB, ws + BKB, ws + BVB,
      ws + QOFF, ws + KOFF, ws + VTOFF, nullptr, 3072, 1024);
  flash_attn<<<dim3(16, 64), 256, 0, stream>>>(ws + QOFF, ws + KOFF, ws + VTOFF, ws + HCOFF);
  gemm128<1><<<dim3(32, 64), 256, 0, stream>>>(
      ws + HCOFF, ws + W1B, nullptr, nullptr, ws + B1B, nullptr, nullptr,
      ws + HIDOFF, nullptr, nullptr, nullptr, 4096, 1024);
  gemm128<0><<<dim3(8, 64), 256, 0, stream>>>(
      ws + HIDOFF, ws + W2B, nullptr, nullptr, ws + B2B, nullptr, nullptr,
      nullptr, nullptr, nullptr, out, 1024, 4096);
}

// Round 7
// 410.490 us; speedup vs baseline: 1.3846x; 1.0424x over previous
//
#include <hip/hip_runtime.h>
#include <stdint.h>

// ---------------------------------------------------------------------------
// OwnMultiHeadTransformer: B=4, S=2048, D=1024, H=16, HD=64, FF=4096
// fp32 I/O, bf16 MFMA internal.
//   0) cvt_all: fp32 inputs -> bf16 in d_ws
//   1) gemm128<2>: QKV projection; Q scaled by log2e/32; V stored transposed
//   2) flash_attn: no-max exp2 softmax, S^T orientation (R3)
//   3) gemm128<1>: FFN1 + relu
//   4) gemm128<0>: FFN2 -> d_out (fp32)
// R7: gemm128 __launch_bounds__ (256,2) -> (256,4). Evidence: every (256,2)
//     kernel measures ~25% occupancy (= exactly 2 blocks/CU) despite LDS/VGPR
//     headroom for 5 — the waves/EU declaration acts as the achieved
//     residency, and 8 waves/CU leaves all pipes idle (R6 QKV: Mfma 19%,
//     VALU 14%, HBM 11%). 4 blocks x 32KB = 128KB <= 160KB LDS.
// ---------------------------------------------------------------------------

typedef __attribute__((ext_vector_type(8))) short bf16x8;
typedef __attribute__((ext_vector_type(4))) float f32x4;

__device__ __forceinline__ float bf2f(unsigned short u) {
  union { float f; uint32_t i; } v; v.i = ((uint32_t)u) << 16; return v.f;
}
__device__ __forceinline__ unsigned short f2bf(float f) {
  union { float f; uint32_t i; } v; v.f = f;
  uint32_t i = v.i;
  return (unsigned short)((i + 0x7fffu + ((i >> 16) & 1u)) >> 16);  // RNE
}

#if __has_builtin(__builtin_amdgcn_exp2f)
#define EXP2(x) __builtin_amdgcn_exp2f(x)
#else
#define EXP2(x) __expf((x) * 0.6931471805599453f)
#endif

// pack two f32 -> two bf16 (round-half-up) in one u32; lo gets p0
__device__ __forceinline__ uint32_t pk_bf16(float p0, float p1) {
  union { float f; uint32_t i; } a, b; a.f = p0; b.f = p1;
  return __builtin_amdgcn_perm(b.i + 0x8000u, a.i + 0x8000u, 0x07060302u);
}

// async 16B global->LDS (wave-uniform base + lane*16 via tid-linear chunks)
__device__ __forceinline__ void gld16(const void* g, void* l) {
  __builtin_amdgcn_global_load_lds(
      (const __attribute__((address_space(1))) uint32_t*)(uintptr_t)g,
      (__attribute__((address_space(3))) uint32_t*)(uintptr_t)l, 16, 0, 0);
}

#define SCALE_Q 0.04508422002778011f  /* log2(e) / sqrt(D=1024) */

// ---- ws layout (bf16 element offsets) -------------------------------------
#define W1B          0
#define W2B    4194304
#define B1B    8388608
#define B2B    8392704
#define BQB    8393728
#define BKB    8394752
#define BVB    8395776
#define EMBB   8396800
#define WQB   16785408
#define WKB   17833984
#define WVB   18882560
#define QOFF  19931136
#define KOFF  28319744
#define VTOFF 36708352
#define HCOFF 45096960        /* peak 53485568 elems = 102 MiB */
#define HIDOFF 8396800        /* hid overlays dead emb/Wqkv regions */

// ---- 0) fp32 -> bf16 ------------------------------------------------------
__global__ void cvt_all(const float* __restrict__ emb, const float* __restrict__ Wq,
                        const float* __restrict__ bq,  const float* __restrict__ Wk,
                        const float* __restrict__ bk,  const float* __restrict__ Wv,
                        const float* __restrict__ bv,  const float* __restrict__ W1,
                        const float* __restrict__ b1,  const float* __restrict__ W2,
                        const float* __restrict__ b2,  unsigned short* __restrict__ ws) {
  const int i4 = blockIdx.x * 256 + threadIdx.x;
  if (i4 >= 4982784) return;
  const float* s; unsigned short* d; int base;
  if      (i4 < 2097152) { s = emb; d = ws + EMBB; base = 0; }
  else if (i4 < 2359296) { s = Wq;  d = ws + WQB;  base = 2097152; }
  else if (i4 < 2621440) { s = Wk;  d = ws + WKB;  base = 2359296; }
  else if (i4 < 2883584) { s = Wv;  d = ws + WVB;  base = 2621440; }
  else if (i4 < 3932160) { s = W1;  d = ws + W1B;  base = 2883584; }
  else if (i4 < 4980736) { s = W2;  d = ws + W2B;  base = 3932160; }
  else if (i4 < 4980992) { s = bq;  d = ws + BQB;  base = 4980736; }
  else if (i4 < 4981248) { s = bk;  d = ws + BKB;  base = 4980992; }
  else if (i4 < 4981504) { s = bv;  d = ws + BVB;  base = 4981248; }
  else if (i4 < 4982528) { s = b1;  d = ws + B1B;  base = 4981504; }
  else                   { s = b2;  d = ws + B2B;  base = 4982528; }
  const int j = i4 - base;
  const float4 v = ((const float4*)s)[j];
  ushort4 o;
  o.x = f2bf(v.x); o.y = f2bf(v.y); o.z = f2bf(v.z); o.w = f2bf(v.w);
  *(ushort4*)(d + (size_t)j * 4) = o;
}

// ---- GEMM: MODE 0 = bias (fp32 out), 1 = bias+relu, 2 = QKV routing -------
// 128x128 tile, BK=64. Requires K % 64 == 0 and 64 total row-tiles.
template <int MODE>
__launch_bounds__(256, 4)
__global__ void gemm128(const unsigned short* __restrict__ A,
                        const unsigned short* __restrict__ W0,
                        const unsigned short* __restrict__ W1p,
                        const unsigned short* __restrict__ W2p,
                        const unsigned short* __restrict__ bias0,
                        const unsigned short* __restrict__ bias1,
                        const unsigned short* __restrict__ bias2,
                        unsigned short* __restrict__ out0,
                        unsigned short* __restrict__ out1,
                        unsigned short* __restrict__ out2,
                        float* __restrict__ foutp,
                        int N, int K) {
  __shared__ unsigned short At[128 * 64];
  __shared__ unsigned short Bt[128 * 64];
  const int tid  = threadIdx.x;
  const int wave = tid >> 6, lane = tid & 63;
  const int quad = lane >> 4, l15 = lane & 15;

  // XCD swizzle: xcd = lid&7 owns rows ≡ xcd (mod 8), col-panels of 8.
  const int lid = blockIdx.x + blockIdx.y * gridDim.x;
  const int s_ = lid >> 3;
  const int rowBase = (((lid & 7) + ((s_ & 7) << 3)) << 7);
  const int colBase = ((s_ >> 3) << 7);

  const unsigned short* W = W0;
  const unsigned short* bias = bias0;
  int colW = colBase;
  if (MODE == 2) {
    const int which = colBase >> 10;
    if (which == 1) { W = W1p; bias = bias1; }
    if (which == 2) { W = W2p; bias = bias2; }
    colW = colBase & 1023;
  }

  // Staging: 1024 16B chunks/tile; phys chunk u = row*8 + cc holds logical
  // k-chunk ec = cc ^ (row&7). 8 consecutive lanes = one row's full 128B.
  const unsigned short* gA[4]; const unsigned short* gB[4];
  unsigned short *lA[4], *lB[4];
#pragma unroll
  for (int i = 0; i < 4; ++i) {
    const int u = tid + 256 * i;
    const int r = u >> 3, e = (((u & 7) ^ (r & 7)) * 8);
    gA[i] = A + (size_t)(rowBase + r) * K + e;
    gB[i] = W + (size_t)(colW + r) * K + e;
    lA[i] = At + u * 8;
    lB[i] = Bt + u * 8;
  }

  // Fragment offsets: row ra, logical k-chunk q8 = quad + 4*kk ->
  // addr = ra*64 + ((q8 ^ (ra&7))*8). 128B rows -> worst 2-way (free).
  const int wrow = (wave & 1) * 64, wcol = (wave >> 1) * 64;
  int aoff[2][4], boff[2][4];
#pragma unroll
  for (int kk = 0; kk < 2; ++kk)
#pragma unroll
    for (int t = 0; t < 4; ++t) {
      const int ra = wrow + t * 16 + l15;
      aoff[kk][t] = ra * 64 + (((quad + 4 * kk) ^ (ra & 7)) * 8);
      const int rb = wcol + t * 16 + l15;
      boff[kk][t] = rb * 64 + (((quad + 4 * kk) ^ (rb & 7)) * 8);
    }

  f32x4 acc[4][4] = {};
  for (int k0 = 0; k0 < K; k0 += 64) {
    __syncthreads();
#pragma unroll
    for (int i = 0; i < 4; ++i) { gld16(gA[i], lA[i]); gld16(gB[i], lB[i]); }
#pragma unroll
    for (int i = 0; i < 4; ++i) { gA[i] += 64; gB[i] += 64; }
    __syncthreads();
#pragma unroll
    for (int kk = 0; kk < 2; ++kk) {
      bf16x8 af[4], bfr[4];
#pragma unroll
      for (int t = 0; t < 4; ++t) af[t]  = *(const bf16x8*)(At + aoff[kk][t]);
#pragma unroll
      for (int t = 0; t < 4; ++t) bfr[t] = *(const bf16x8*)(Bt + boff[kk][t]);
#pragma unroll
      for (int mt = 0; mt < 4; ++mt)
#pragma unroll
        for (int nt = 0; nt < 4; ++nt)
          acc[mt][nt] = __builtin_amdgcn_mfma_f32_16x16x32_bf16(
              af[mt], bfr[nt], acc[mt][nt], 0, 0, 0);
    }
  }

#pragma unroll
  for (int mt = 0; mt < 4; ++mt) {
    const int row = rowBase + wrow + mt * 16 + quad * 4;
#pragma unroll
    for (int nt = 0; nt < 4; ++nt) {
      const int cIn = colW + wcol + nt * 16 + l15;
      const float bv = bf2f(bias[cIn]);
      if (MODE == 2) {
        const int which = colBase >> 10;
        const int h = cIn >> 6, e = cIn & 63;
#pragma unroll
        for (int r = 0; r < 4; ++r) {
          const int tok = row + r;
          const int b = tok >> 11, s = tok & 2047;
          const float v = acc[mt][nt][r] + bv;
          const size_t bh = (size_t)(b * 16 + h);
          if (which == 0)      out0[(bh * 2048 + s) * 64 + e] = f2bf(v * SCALE_Q);
          else if (which == 1) out1[(bh * 2048 + s) * 64 + e] = f2bf(v);
          else                 out2[(bh * 64 + e) * 2048 + s] = f2bf(v);  // V^T
        }
      } else if (MODE == 1) {
#pragma unroll
        for (int r = 0; r < 4; ++r) {
          const float v = fmaxf(acc[mt][nt][r] + bv, 0.0f);
          out0[(size_t)(row + r) * N + cIn] = f2bf(v);
        }
      } else {
#pragma unroll
        for (int r = 0; r < 4; ++r)
          foutp[(size_t)(row + r) * N + cIn] = acc[mt][nt][r] + bv;
      }
    }
  }
}

// ---- flash attention (R3): S^T orientation, no-max exp2 softmax -----------
// grid (16, 64): logical (q-block, b*16+h); XCD-swizzled.
__launch_bounds__(256, 4)
__global__ void flash_attn(const unsigned short* __restrict__ Q,
                           const unsigned short* __restrict__ Kg,
                           const unsigned short* __restrict__ Vt,
                           unsigned short* __restrict__ Hc) {
  __shared__ unsigned short Kt[64 * 64];     // K tile [t][e], chunk-swizzled
  __shared__ unsigned short Vs[64 * 64];     // V^T tile [e][t], chunk-swizzled
  __shared__ unsigned short Pl[4][32 * 64];  // per-wave P [q][t], chunk-swizzled
  __shared__ float Lb[4][32];                // per-wave row sums
  const int tid  = threadIdx.x;
  const int wave = tid >> 6, lane = tid & 63;
  const int quad = lane >> 4, l15 = lane & 15;

  // XCD swizzle: 8 bh's per XCD, q-blocks iterated within -> KV hot in L2.
  const int lid = blockIdx.x + blockIdx.y * gridDim.x;
  const int s_ = lid >> 3;
  const int bh = (lid & 7) + ((s_ & 7) << 3);
  const int q0 = ((s_ >> 3) << 7) + wave * 32;

  const size_t base = (size_t)bh * (2048 * 64);
  const unsigned short* Qb = Q  + base;
  const unsigned short* Kb = Kg + base;
  const unsigned short* Vb = Vt + base;   // [64 e][2048 t]

  // Q fragments (MFMA B operand for S^T: n=q=l15, k=e=quad*8+j)
  bf16x8 qf[2][2];
#pragma unroll
  for (int qt = 0; qt < 2; ++qt) {
    const int q = q0 + qt * 16 + l15;
#pragma unroll
    for (int kk = 0; kk < 2; ++kk)
      qf[qt][kk] = *(const bf16x8*)(Qb + (size_t)q * 64 + kk * 32 + quad * 8);
  }

  // KV staging (8-elem chunk swizzle: ec = cc ^ (row&7); 8 lanes = one 128B row)
  const int u0 = tid, u1 = tid + 256;
  const int kr0 = u0 >> 3, kc0 = (((u0 & 7) ^ (kr0 & 7)) * 8);
  const int kr1 = u1 >> 3, kc1 = (((u1 & 7) ^ (kr1 & 7)) * 8);
  const unsigned short* gK0 = Kb + (size_t)kr0 * 64 + kc0;
  const unsigned short* gK1 = Kb + (size_t)kr1 * 64 + kc1;
  const unsigned short* gV0 = Vb + (size_t)kr0 * 2048 + kc0;
  const unsigned short* gV1 = Vb + (size_t)kr1 * 2048 + kc1;
  unsigned short* lK0 = Kt + u0 * 8;
  unsigned short* lK1 = Kt + u1 * 8;
  unsigned short* lV0 = Vs + u0 * 8;
  unsigned short* lV1 = Vs + u1 * 8;

  float l_acc[2] = {0.0f, 0.0f};
  f32x4 o[2][4] = {};
  unsigned short* Pw = Pl[wave];

  for (int it = 0; it < 32; ++it) {
    __syncthreads();
    gld16(gK0, lK0); gld16(gK1, lK1);
    gld16(gV0, lV0); gld16(gV1, lV1);
    gK0 += 4096; gK1 += 4096; gV0 += 64; gV1 += 64;
    __syncthreads();

    // S^T = K Q^T : C row = t_local = tt*16+quad*4+r, col = q = qt*16+l15
    f32x4 st[4][2] = {};
#pragma unroll
    for (int tt = 0; tt < 4; ++tt) {
      const int t = tt * 16 + l15;
      const bf16x8 kf0 = *(const bf16x8*)(Kt + t * 64 + ((quad       ^ (t & 7)) * 8));
      const bf16x8 kf1 = *(const bf16x8*)(Kt + t * 64 + (((quad + 4) ^ (t & 7)) * 8));
#pragma unroll
      for (int qt = 0; qt < 2; ++qt) {
        st[tt][qt] = __builtin_amdgcn_mfma_f32_16x16x32_bf16(kf0, qf[qt][0], st[tt][qt], 0, 0, 0);
        st[tt][qt] = __builtin_amdgcn_mfma_f32_16x16x32_bf16(kf1, qf[qt][1], st[tt][qt], 0, 0, 0);
      }
    }

    // p = exp2(s) (no max: scores bounded), lane-local l, pack -> P[q][t] LDS
#pragma unroll
    for (int tt = 0; tt < 4; ++tt) {
      const int tc = tt * 2 + (quad >> 1);
#pragma unroll
      for (int qt = 0; qt < 2; ++qt) {
        const float p0 = EXP2(st[tt][qt][0]);
        const float p1 = EXP2(st[tt][qt][1]);
        const float p2 = EXP2(st[tt][qt][2]);
        const float p3 = EXP2(st[tt][qt][3]);
        l_acc[qt] += (p0 + p1) + (p2 + p3);
        uint2 w;
        w.x = pk_bf16(p0, p1);
        w.y = pk_bf16(p2, p3);
        const int qrow = qt * 16 + l15;
        *(uint2*)(Pw + qrow * 64 + ((tc ^ (qrow & 7)) * 8) + (quad & 1) * 4) = w;
      }
    }

    // O += P V (same-wave LDS round-trip, ordered by lgkmcnt)
    bf16x8 pf[2][2];
#pragma unroll
    for (int mt = 0; mt < 2; ++mt) {
      const int qq = mt * 16 + l15;
      pf[mt][0] = *(const bf16x8*)(Pw + qq * 64 + ((quad       ^ (qq & 7)) * 8));
      pf[mt][1] = *(const bf16x8*)(Pw + qq * 64 + (((quad + 4) ^ (qq & 7)) * 8));
    }
#pragma unroll
    for (int nt = 0; nt < 4; ++nt) {
      const int e = nt * 16 + l15;
      const bf16x8 vf0 = *(const bf16x8*)(Vs + e * 64 + ((quad       ^ (e & 7)) * 8));
      const bf16x8 vf1 = *(const bf16x8*)(Vs + e * 64 + (((quad + 4) ^ (e & 7)) * 8));
#pragma unroll
      for (int mt = 0; mt < 2; ++mt) {
        o[mt][nt] = __builtin_amdgcn_mfma_f32_16x16x32_bf16(pf[mt][0], vf0, o[mt][nt], 0, 0, 0);
        o[mt][nt] = __builtin_amdgcn_mfma_f32_16x16x32_bf16(pf[mt][1], vf1, o[mt][nt], 0, 0, 0);
      }
    }
  }

  // l: reduce across quads, publish per-q via LDS, fetch per C-row
#pragma unroll
  for (int qt = 0; qt < 2; ++qt) {
    float v = l_acc[qt];
    v += __shfl_xor(v, 16, 64);
    v += __shfl_xor(v, 32, 64);
    Lb[wave][qt * 16 + l15] = v;
  }
  const f32x4 lv0 = *(const f32x4*)&Lb[wave][quad * 4];
  const f32x4 lv1 = *(const f32x4*)&Lb[wave][16 + quad * 4];

  const int b = bh >> 4, h = bh & 15;
#pragma unroll
  for (int mt = 0; mt < 2; ++mt)
#pragma unroll
    for (int r = 0; r < 4; ++r) {
      const int qg = q0 + mt * 16 + quad * 4 + r;
      const float inv = __builtin_amdgcn_rcpf(mt == 0 ? lv0[r] : lv1[r]);
#pragma unroll
      for (int nt = 0; nt < 4; ++nt) {
        const int e = nt * 16 + l15;
        Hc[((size_t)b * 2048 + qg) * 1024 + h * 64 + e] = f2bf(o[mt][nt][r] * inv);
      }
    }
}

extern "C" void kernel_launch(void* const* d_in, const int* in_sizes, int n_in,
                              void* d_out, int out_size, void* d_ws, size_t ws_size,
                              hipStream_t stream) {
  const float* emb = (const float*)d_in[0];
  const float* Wq  = (const float*)d_in[1];
  const float* bq  = (const float*)d_in[2];
  const float* Wk  = (const float*)d_in[3];
  const float* bk  = (const float*)d_in[4];
  const float* Wv  = (const float*)d_in[5];
  const float* bv  = (const float*)d_in[6];
  const float* W1  = (const float*)d_in[7];
  const float* b1  = (const float*)d_in[8];
  const float* W2  = (const float*)d_in[9];
  const float* b2  = (const float*)d_in[10];

  unsigned short* ws = (unsigned short*)d_ws;
  float* out = (float*)d_out;

  cvt_all<<<19465, 256, 0, stream>>>(emb, Wq, bq, Wk, bk, Wv, bv, W1, b1, W2, b2, ws);
  gemm128<2><<<dim3(24, 64), 256, 0, stream>>>(
      ws + EMBB, ws + WQB, ws + WKB, ws + WVB, ws + BQB, ws + BKB, ws + BVB,
      ws + QOFF, ws + KOFF, ws + VTOFF, nullptr, 3072, 1024);
  flash_attn<<<dim3(16, 64), 256, 0, stream>>>(ws + QOFF, ws + KOFF, ws + VTOFF, ws + HCOFF);
  gemm128<1><<<dim3(32, 64), 256, 0, stream>>>(
      ws + HCOFF, ws + W1B, nullptr, nullptr, ws + B1B, nullptr, nullptr,
      ws + HIDOFF, nullptr, nullptr, nullptr, 4096, 1024);
  gemm128<0><<<dim3(8, 64), 256, 0, stream>>>(
      ws + HIDOFF, ws + W2B, nullptr, nullptr, ws + B2B, nullptr, nullptr,
      nullptr, nullptr, nullptr, out, 1024, 4096);
}